// Round 9
// baseline (117.585 us; speedup 1.0000x reference)
//
#include <hip/hip_runtime.h>
#include <math.h>

#define B_SZ 1024
#define Z_DIM 512
#define A_DIM 8
#define AH 64
#define ZH 512
#define NNEG 99
#define INV_T 10.0f
#define RNP 104   // rnall row pitch
#define TBB 16    // neg: b rows per block
#define TSS 13    // neg: shifts per block

typedef __attribute__((ext_vector_type(8))) short short8;   // 8 bf16 (16 B)
typedef __attribute__((ext_vector_type(4))) short short4b;  // 4 bf16 (8 B)
typedef __attribute__((ext_vector_type(4))) float f32x4;

// fp32 -> bf16 round-to-nearest-even (unbiased; rel err <= 2^-9)
__device__ __forceinline__ short bf16rn(float x) {
    unsigned u = __float_as_uint(x);
    u += 0x7fffu + ((u >> 16) & 1u);
    return (short)(u >> 16);
}
__device__ __forceinline__ void cvt8rn(float4 x0, float4 x1, short8& h) {
    h[0] = bf16rn(x0.x); h[1] = bf16rn(x0.y); h[2] = bf16rn(x0.z); h[3] = bf16rn(x0.w);
    h[4] = bf16rn(x1.x); h[5] = bf16rn(x1.y); h[6] = bf16rn(x1.z); h[7] = bf16rn(x1.w);
}

// XOR-swizzled 16B-unit index into a [rows][8 units] bf16 tile (no padding).
__device__ __forceinline__ int sw(int m, int kb) { return m * 8 + (kb ^ (m & 7)); }

#define VMWAIT(N) asm volatile("s_waitcnt vmcnt(" #N ")" ::: "memory")
__device__ __forceinline__ void raw_barrier() {
    asm volatile("" ::: "memory");
    __builtin_amdgcn_s_barrier();
    asm volatile("" ::: "memory");
}
typedef const __attribute__((address_space(1))) void* gas_ptr;
typedef __attribute__((address_space(3))) void* las_ptr;
__device__ __forceinline__ void gld_lds16(const void* gsrc, void* ldst) {
    __builtin_amdgcn_global_load_lds((gas_ptr)gsrc, (las_ptr)ldst, 16, 0, 0);
}

// ---------------------------------------------------------------------------
// cvt (unchanged, verified): one-shot bf16 conversion of all GEMM operands.
__global__ __launch_bounds__(256) void cvt_kernel(
    const float* __restrict__ z, const float* __restrict__ z_next,
    const float* __restrict__ z_next_hat, const float* __restrict__ W1,
    const float* __restrict__ W2, const float* __restrict__ actions,
    const float* __restrict__ Wa, const float* __restrict__ ba,
    short* __restrict__ zb, short* __restrict__ znb, short* __restrict__ znhb,
    short* __restrict__ w1t, short* __restrict__ w2b, short* __restrict__ hab)
{
    const int id = blockIdx.x, tid = threadIdx.x;
    if (id < 896) {   // elementwise cvt, 2048 elems/block
        const float* src; short* dst; int local;
        if (id < 256)      { src = z;          dst = zb;   local = id; }
        else if (id < 512) { src = z_next;     dst = znb;  local = id - 256; }
        else if (id < 768) { src = z_next_hat; dst = znhb; local = id - 512; }
        else               { src = W2;         dst = w2b;  local = id - 768; }
        int i8 = local * 2048 + tid * 8;
        float4 x0 = *(const float4*)&src[i8];
        float4 x1 = *(const float4*)&src[i8 + 4];
        short8 h; cvt8rn(x0, x1, h);
        *(short8*)&dst[i8] = h;
    } else if (id < 968) {   // W1 transpose tile -> bf16
        __shared__ float L[64][68];
        int local = id - 896, kt = local >> 3, nt = local & 7;
#pragma unroll
        for (int i = 0; i < 4; ++i) {
            int f = tid + i * 256;
            int r = f >> 4, c4 = (f & 15) << 2;
            *(float4*)&L[r][c4] = *(const float4*)&W1[(kt * 64 + r) * 512 + nt * 64 + c4];
        }
        __syncthreads();
#pragma unroll
        for (int i = 0; i < 4; ++i) {
            int f = tid + i * 256;
            int r = f >> 4, c4 = (f & 15) << 2;
            short4b o = {bf16rn(L[c4][r]), bf16rn(L[c4 + 1][r]),
                         bf16rn(L[c4 + 2][r]), bf16rn(L[c4 + 3][r])};
            *(short4b*)&w1t[(nt * 64 + r) * 576 + kt * 64 + c4] = o;
        }
    } else {                 // ha tile -> bf16
        __shared__ float sWa[A_DIM * 64];
        __shared__ float sba[64];
        int j0 = (id - 968) * 64;
        for (int i = tid; i < A_DIM * 64; i += 256) sWa[i] = Wa[i];
        if (tid < 64) sba[tid] = ba[tid];
        __syncthreads();
        int r = tid >> 2, c0 = (tid & 3) * 16;
        float4 a0 = *(const float4*)&actions[(j0 + r) * A_DIM + 0];
        float4 a1 = *(const float4*)&actions[(j0 + r) * A_DIM + 4];
        float av[8] = {a0.x, a0.y, a0.z, a0.w, a1.x, a1.y, a1.z, a1.w};
        float o[16];
#pragma unroll
        for (int c = 0; c < 16; ++c) o[c] = sba[c0 + c];
#pragma unroll
        for (int k = 0; k < A_DIM; ++k)
#pragma unroll
            for (int c = 0; c < 16; ++c) o[c] += av[k] * sWa[k * 64 + c0 + c];
#pragma unroll
        for (int c = 0; c < 16; c += 4) {
            short4b h = {bf16rn(fmaxf(o[c], 0.f)),     bf16rn(fmaxf(o[c + 1], 0.f)),
                         bf16rn(fmaxf(o[c + 2], 0.f)), bf16rn(fmaxf(o[c + 3], 0.f))};
            *(short4b*)&hab[(j0 + r) * 64 + c0 + c] = h;
        }
    }
}

// ---------------------------------------------------------------------------
// mm v8 (unchanged, verified R7/R8): 128x128-tile BK=64 NT MFMA GEMM on bf16,
// global_load_lds width-16 staging, source-side XOR pre-swizzle.  160 blocks.
__global__ __launch_bounds__(256, 2) void mm_kernel(
    const short* __restrict__ zb, const short* __restrict__ znb,
    const short* __restrict__ znhb, const short* __restrict__ w1t,
    const short* __restrict__ w2b, const short* __restrict__ hab,
    const float* __restrict__ b1,
    float* __restrict__ sim, float* __restrict__ u, float* __restrict__ v,
    float* __restrict__ g)
{
    __shared__ __align__(16) short Ah[128 * 64], Bh[128 * 64];   // 16 KB each

    const int id = blockIdx.x;
    const int tid = threadIdx.x;

    const short* A; const short* B; const float* bias = nullptr;
    float* C; int N, K, lda, ldb, bm0, bn0;
    if (id < 64) {
        bm0 = (id >> 3) * 128; bn0 = (id & 7) * 128;
        A = znb; lda = 512; B = znhb; ldb = 512; C = sim; N = 1024; K = 512;
    } else if (id < 96) {
        int t = id - 64; bm0 = (t >> 2) * 128; bn0 = (t & 3) * 128;
        A = zb; lda = 512; B = w1t; ldb = 576; C = u; N = 512; K = 512; bias = b1;
    } else if (id < 128) {
        int t = id - 96; bm0 = (t >> 2) * 128; bn0 = (t & 3) * 128;
        A = znb; lda = 512; B = w2b; ldb = 512; C = v; N = 512; K = 512;
    } else {
        int t = id - 128; bm0 = (t >> 2) * 128; bn0 = (t & 3) * 128;
        A = hab; lda = 64; B = w1t + 512; ldb = 576; C = g; N = 512; K = 64;
    }

    const int lane = tid & 63, wv = tid >> 6;
    const int lm = lane & 15, lq = lane >> 4;
    const int wr = (wv >> 1) * 64, wc = (wv & 1) * 64;
    short8* A8 = (short8*)Ah; short8* B8 = (short8*)Bh;
    f32x4 acc[4][4] = {};

    for (int k0 = 0; k0 < K; k0 += 64) {
#pragma unroll
        for (int q = 0; q < 4; ++q) {
            int f = q * 256 + tid;           // 0..1023: row = f>>3, unit = f&7
            int row = f >> 3;
            int ug = (f & 7) ^ (row & 7);    // inverse swizzle on the source
            gld_lds16(&A[(bm0 + row) * lda + k0 + ug * 8],
                      &Ah[(q * 256 + wv * 64) * 8]);
            gld_lds16(&B[(bn0 + row) * ldb + k0 + ug * 8],
                      &Bh[(q * 256 + wv * 64) * 8]);
        }
        VMWAIT(0);
        raw_barrier();
#pragma unroll
        for (int kk = 0; kk < 64; kk += 32) {
            int kbi = (kk >> 3) + lq;
            short8 ah[4], bh[4];
#pragma unroll
            for (int i = 0; i < 4; ++i) ah[i] = A8[sw(wr + i * 16 + lm, kbi)];
#pragma unroll
            for (int j = 0; j < 4; ++j) bh[j] = B8[sw(wc + j * 16 + lm, kbi)];
#pragma unroll
            for (int i = 0; i < 4; ++i)
#pragma unroll
                for (int j = 0; j < 4; ++j)
                    acc[i][j] = __builtin_amdgcn_mfma_f32_16x16x32_bf16(ah[i], bh[j], acc[i][j], 0, 0, 0);
        }
        raw_barrier();
    }
#pragma unroll
    for (int i = 0; i < 4; ++i)
#pragma unroll
        for (int j = 0; j < 4; ++j) {
            int n = bn0 + wc + j * 16 + lm;
            float bb = bias ? bias[n] : 0.0f;
#pragma unroll
            for (int r = 0; r < 4; ++r) {
                int m = bm0 + wr + i * 16 + lq * 4 + r;
                C[m * N + n] = acc[i][j][r] + bb;
            }
        }
}

// ---------------------------------------------------------------------------
// neg v11: tiled-reuse negatives.  Old v10 re-read g with ZERO reuse: 1024
// blocks x 13 octets x (16KB g + 4KB u/v) = 266 MB of L2/L3 traffic — at L3
// bandwidth that's ~25-30us, the dominant blob component.  New: block =
// (16 b-rows) x (13 shifts).  Needed g rows j=b+s form ONE CONTIGUOUS 28-row
// band -> staged once in LDS (56KB).  u/v for the block's 16 rows live in
// registers (4 rows/wave).  Traffic: 512 blocks x 120KB = 61MB (4.4x less),
// inner loop is pure LDS+VALU.  512 blocks = 2/CU (LDS-limited).
__global__ __launch_bounds__(256, 2) void neg_kernel(
    const float* __restrict__ u, const float* __restrict__ v,
    const float* __restrict__ g, float* __restrict__ rnall)
{
    __shared__ float gl[TBB + TSS - 1][512];   // 28 x 2KB = 56KB
    const int b0 = blockIdx.x * TBB;
    const int s0 = 1 + blockIdx.y * TSS;
    const int tid = threadIdx.x;
    const int w = tid >> 6, lane = tid & 63;

    // stage the 28-row diagonal g band (coalesced float4)
    for (int i = tid; i < (TBB + TSS - 1) * 128; i += 256) {
        int r = i >> 7, c4 = (i & 127) << 2;
        int j = (b0 + s0 + r) & (B_SZ - 1);
        *(float4*)&gl[r][c4] = *(const float4*)&g[j * 512 + c4];
    }

    // register-cache u/v for this wave's 4 b rows
    const int bb = b0 + w * 4;
    float4 ua[4], ub[4], va[4], vb[4];
#pragma unroll
    for (int i = 0; i < 4; ++i) {
        ua[i] = *(const float4*)&u[(bb + i) * 512 + lane * 4];
        ub[i] = *(const float4*)&u[(bb + i) * 512 + 256 + lane * 4];
        va[i] = *(const float4*)&v[(bb + i) * 512 + lane * 4];
        vb[i] = *(const float4*)&v[(bb + i) * 512 + 256 + lane * 4];
    }
    __syncthreads();

    for (int si = 0; si < TSS; ++si) {
        int s = s0 + si;
        if (s > NNEG) break;                   // block-uniform
        float d[4];
#pragma unroll
        for (int i = 0; i < 4; ++i) {
            int r = w * 4 + i + si;            // g row for (b=bb+i, s)
            float4 g0 = *(const float4*)&gl[r][lane * 4];
            float4 g1 = *(const float4*)&gl[r][256 + lane * 4];
            float t = 0.0f;
            t += fmaxf(ua[i].x + g0.x, 0.0f) * va[i].x;
            t += fmaxf(ua[i].y + g0.y, 0.0f) * va[i].y;
            t += fmaxf(ua[i].z + g0.z, 0.0f) * va[i].z;
            t += fmaxf(ua[i].w + g0.w, 0.0f) * va[i].w;
            t += fmaxf(ub[i].x + g1.x, 0.0f) * vb[i].x;
            t += fmaxf(ub[i].y + g1.y, 0.0f) * vb[i].y;
            t += fmaxf(ub[i].z + g1.z, 0.0f) * vb[i].z;
            t += fmaxf(ub[i].w + g1.w, 0.0f) * vb[i].w;
            d[i] = t;
        }
        for (int off = 32; off; off >>= 1) {
#pragma unroll
            for (int i = 0; i < 4; ++i) d[i] += __shfl_down(d[i], off);
        }
        if (lane == 0) {
#pragma unroll
            for (int i = 0; i < 4; ++i)
                rnall[(bb + i) * RNP + s - 1] = d[i];
        }
    }
}

// ---------------------------------------------------------------------------
// smax (unchanged, verified R8): 1024 blocks x 256 threads.
__global__ __launch_bounds__(256) void smax_kernel(
    const float* __restrict__ sim, const float* __restrict__ rnall,
    const float* __restrict__ z, const float* __restrict__ z_next,
    const float* __restrict__ b2, float* __restrict__ pw)
{
    const int b = blockIdx.x;
    const int tid = threadIdx.x;
    const int w = tid >> 6, lane = tid & 63;
    __shared__ float sred[12];

    float4 s4 = *(const float4*)&sim[b * 1024 + tid * 4];
    float rawn = (tid < NNEG) ? rnall[b * RNP + tid] : 0.0f;
    float diag = sim[b * 1024 + b];

    // c0: each thread covers 2 elements
    float2 z2 = *(const float2*)&z[b * 512 + tid * 2];
    float2 n2 = *(const float2*)&z_next[b * 512 + tid * 2];
    float2 c2 = *(const float2*)&b2[tid * 2];
    float p = (z2.x + c2.x) * n2.x + (z2.y + c2.y) * n2.y;
    for (int off = 32; off; off >>= 1) p += __shfl_down(p, off);
    if (lane == 0) sred[w] = p;
    __syncthreads();
    const float c0 = sred[0] + sred[1] + sred[2] + sred[3];
    __syncthreads();

    float neg = (tid < NNEG) ? (rawn + c0) : -3.4e38f;

    float m = fmaxf(fmaxf(s4.x, s4.y), fmaxf(s4.z, s4.w));
    m = fmaxf(m, neg);
    for (int off = 32; off; off >>= 1) m = fmaxf(m, __shfl_xor(m, off));
    if (lane == 0) sred[w] = m;
    __syncthreads();
    m = fmaxf(fmaxf(sred[0], sred[1]), fmaxf(sred[2], sred[3]));

    float es = 0.0f; int ck = 0;
    {
        float xs[4] = {s4.x, s4.y, s4.z, s4.w};
#pragma unroll
        for (int c = 0; c < 4; ++c) {
            int j = tid * 4 + c;
            float x = xs[c];
            es += __expf((x - m) * INV_T);
            if (x > diag) ck++;
            else if (j < b && x == diag) ck++;   // tie-break: lower index wins
        }
    }
    if (tid < NNEG) {
        es += __expf((neg - m) * INV_T);
        if (neg > diag) ck++;
    }
    float ckf = (float)ck;
    for (int off = 32; off; off >>= 1) {
        es += __shfl_down(es, off);
        ckf += __shfl_down(ckf, off);
    }
    if (lane == 0) { sred[4 + w] = es; sred[8 + w] = ckf; }
    __syncthreads();
    if (tid == 0) {
        float est = sred[4] + sred[5] + sred[6] + sred[7];
        int ckt = (int)(sred[8] + sred[9] + sred[10] + sred[11]);
        pw[b * 4 + 0] = (m - diag) * INV_T + logf(est);
        pw[b * 4 + 1] = (ckt < 1) ? 1.0f : 0.0f;
        pw[b * 4 + 2] = (ckt < 3) ? 1.0f : 0.0f;
        pw[b * 4 + 3] = (ckt < 10) ? 1.0f : 0.0f;
    }
}

// ---------------------------------------------------------------------------
// final: 1 block x 256 threads, reduce pw[1024][4] -> out[4].
__global__ __launch_bounds__(256) void final_kernel(
    const float* __restrict__ pw, float* __restrict__ out)
{
    __shared__ float red[256];
    const int tid = threadIdx.x;
    const int c = tid & 3;
    float s = 0.0f;
    for (int r = tid >> 2; r < 1024; r += 64) s += pw[r * 4 + c];
    red[tid] = s;
    __syncthreads();
    if (tid < 4) {
        float t = 0.0f;
        for (int q = 0; q < 64; ++q) t += red[tid + q * 4];
        out[tid] = t * (1.0f / (float)B_SZ);
    }
}

// ---------------------------------------------------------------------------
extern "C" void kernel_launch(void* const* d_in, const int* in_sizes, int n_in,
                              void* d_out, int out_size, void* d_ws, size_t ws_size,
                              hipStream_t stream) {
    const float* z          = (const float*)d_in[0];
    const float* z_next     = (const float*)d_in[1];
    const float* z_next_hat = (const float*)d_in[2];
    const float* actions    = (const float*)d_in[3];
    const float* Wa         = (const float*)d_in[4];
    const float* ba         = (const float*)d_in[5];
    const float* W1         = (const float*)d_in[6];
    const float* b1         = (const float*)d_in[7];
    const float* W2         = (const float*)d_in[8];
    const float* b2         = (const float*)d_in[9];
    float* out = (float*)d_out;

    float* ws    = (float*)d_ws;
    float* sim   = ws;                          // 1024*1024
    float* u     = sim + B_SZ * B_SZ;           // 1024*512
    float* v     = u + B_SZ * ZH;               // 1024*512
    float* g     = v + B_SZ * ZH;               // 1024*512
    float* pw    = g + B_SZ * ZH;               // 1024*4
    float* rnall = pw + B_SZ * 4;               // 1024*104
    short* zb    = (short*)(rnall + B_SZ * RNP);
    short* znb   = zb + B_SZ * Z_DIM;
    short* znhb  = znb + B_SZ * Z_DIM;
    short* w1t   = znhb + B_SZ * Z_DIM;         // 512*576
    short* w2b   = w1t + 512 * 576;             // 512*512
    short* hab   = w2b + 512 * 512;             // 1024*64

    cvt_kernel<<<984, 256, 0, stream>>>(z, z_next, z_next_hat, W1, W2,
                                        actions, Wa, ba,
                                        zb, znb, znhb, w1t, w2b, hab);
    mm_kernel<<<160, 256, 0, stream>>>(zb, znb, znhb, w1t, w2b, hab, b1,
                                       sim, u, v, g);
    neg_kernel<<<dim3(B_SZ / TBB, (NNEG + TSS - 1) / TSS), 256, 0, stream>>>(u, v, g, rnall);
    smax_kernel<<<B_SZ, 256, 0, stream>>>(sim, rnall, z, z_next, b2, pw);
    final_kernel<<<1, 256, 0, stream>>>(pw, out);
}

// Round 10
// 115.823 us; speedup vs baseline: 1.0152x; 1.0152x over previous
//
#include <hip/hip_runtime.h>
#include <math.h>

#define B_SZ 1024
#define Z_DIM 512
#define A_DIM 8
#define AH 64
#define ZH 512
#define NNEG 99
#define INV_T 10.0f
#define RNP 104   // rnall row pitch

typedef __attribute__((ext_vector_type(8))) short short8;   // 8 bf16 (16 B)
typedef __attribute__((ext_vector_type(4))) short short4b;  // 4 bf16 (8 B)
typedef __attribute__((ext_vector_type(4))) float f32x4;

// fp32 -> bf16 round-to-nearest-even (unbiased; rel err <= 2^-9)
__device__ __forceinline__ short bf16rn(float x) {
    unsigned u = __float_as_uint(x);
    u += 0x7fffu + ((u >> 16) & 1u);
    return (short)(u >> 16);
}
__device__ __forceinline__ void cvt8rn(float4 x0, float4 x1, short8& h) {
    h[0] = bf16rn(x0.x); h[1] = bf16rn(x0.y); h[2] = bf16rn(x0.z); h[3] = bf16rn(x0.w);
    h[4] = bf16rn(x1.x); h[5] = bf16rn(x1.y); h[6] = bf16rn(x1.z); h[7] = bf16rn(x1.w);
}

// XOR-swizzled 16B-unit index into a [rows][8 units] bf16 tile (no padding).
__device__ __forceinline__ int sw(int m, int kb) { return m * 8 + (kb ^ (m & 7)); }

#define VMWAIT(N) asm volatile("s_waitcnt vmcnt(" #N ")" ::: "memory")
__device__ __forceinline__ void raw_barrier() {
    asm volatile("" ::: "memory");
    __builtin_amdgcn_s_barrier();
    asm volatile("" ::: "memory");
}
typedef const __attribute__((address_space(1))) void* gas_ptr;
typedef __attribute__((address_space(3))) void* las_ptr;
__device__ __forceinline__ void gld_lds16(const void* gsrc, void* ldst) {
    __builtin_amdgcn_global_load_lds((gas_ptr)gsrc, (las_ptr)ldst, 16, 0, 0);
}

// ---------------------------------------------------------------------------
// cvt (unchanged, verified): one-shot bf16 conversion of all GEMM operands.
__global__ __launch_bounds__(256) void cvt_kernel(
    const float* __restrict__ z, const float* __restrict__ z_next,
    const float* __restrict__ z_next_hat, const float* __restrict__ W1,
    const float* __restrict__ W2, const float* __restrict__ actions,
    const float* __restrict__ Wa, const float* __restrict__ ba,
    short* __restrict__ zb, short* __restrict__ znb, short* __restrict__ znhb,
    short* __restrict__ w1t, short* __restrict__ w2b, short* __restrict__ hab)
{
    const int id = blockIdx.x, tid = threadIdx.x;
    if (id < 896) {   // elementwise cvt, 2048 elems/block
        const float* src; short* dst; int local;
        if (id < 256)      { src = z;          dst = zb;   local = id; }
        else if (id < 512) { src = z_next;     dst = znb;  local = id - 256; }
        else if (id < 768) { src = z_next_hat; dst = znhb; local = id - 512; }
        else               { src = W2;         dst = w2b;  local = id - 768; }
        int i8 = local * 2048 + tid * 8;
        float4 x0 = *(const float4*)&src[i8];
        float4 x1 = *(const float4*)&src[i8 + 4];
        short8 h; cvt8rn(x0, x1, h);
        *(short8*)&dst[i8] = h;
    } else if (id < 968) {   // W1 transpose tile -> bf16
        __shared__ float L[64][68];
        int local = id - 896, kt = local >> 3, nt = local & 7;
#pragma unroll
        for (int i = 0; i < 4; ++i) {
            int f = tid + i * 256;
            int r = f >> 4, c4 = (f & 15) << 2;
            *(float4*)&L[r][c4] = *(const float4*)&W1[(kt * 64 + r) * 512 + nt * 64 + c4];
        }
        __syncthreads();
#pragma unroll
        for (int i = 0; i < 4; ++i) {
            int f = tid + i * 256;
            int r = f >> 4, c4 = (f & 15) << 2;
            short4b o = {bf16rn(L[c4][r]), bf16rn(L[c4 + 1][r]),
                         bf16rn(L[c4 + 2][r]), bf16rn(L[c4 + 3][r])};
            *(short4b*)&w1t[(nt * 64 + r) * 576 + kt * 64 + c4] = o;
        }
    } else {                 // ha tile -> bf16
        __shared__ float sWa[A_DIM * 64];
        __shared__ float sba[64];
        int j0 = (id - 968) * 64;
        for (int i = tid; i < A_DIM * 64; i += 256) sWa[i] = Wa[i];
        if (tid < 64) sba[tid] = ba[tid];
        __syncthreads();
        int r = tid >> 2, c0 = (tid & 3) * 16;
        float4 a0 = *(const float4*)&actions[(j0 + r) * A_DIM + 0];
        float4 a1 = *(const float4*)&actions[(j0 + r) * A_DIM + 4];
        float av[8] = {a0.x, a0.y, a0.z, a0.w, a1.x, a1.y, a1.z, a1.w};
        float o[16];
#pragma unroll
        for (int c = 0; c < 16; ++c) o[c] = sba[c0 + c];
#pragma unroll
        for (int k = 0; k < A_DIM; ++k)
#pragma unroll
            for (int c = 0; c < 16; ++c) o[c] += av[k] * sWa[k * 64 + c0 + c];
#pragma unroll
        for (int c = 0; c < 16; c += 4) {
            short4b h = {bf16rn(fmaxf(o[c], 0.f)),     bf16rn(fmaxf(o[c + 1], 0.f)),
                         bf16rn(fmaxf(o[c + 2], 0.f)), bf16rn(fmaxf(o[c + 3], 0.f))};
            *(short4b*)&hab[(j0 + r) * 64 + c0 + c] = h;
        }
    }
}

// ---------------------------------------------------------------------------
// mm v8 (unchanged, verified R7/R8): 128x128-tile BK=64 NT MFMA GEMM on bf16,
// global_load_lds width-16 staging, source-side XOR pre-swizzle.  160 blocks.
__global__ __launch_bounds__(256, 2) void mm_kernel(
    const short* __restrict__ zb, const short* __restrict__ znb,
    const short* __restrict__ znhb, const short* __restrict__ w1t,
    const short* __restrict__ w2b, const short* __restrict__ hab,
    const float* __restrict__ b1,
    float* __restrict__ sim, float* __restrict__ u, float* __restrict__ v,
    float* __restrict__ g)
{
    __shared__ __align__(16) short Ah[128 * 64], Bh[128 * 64];   // 16 KB each

    const int id = blockIdx.x;
    const int tid = threadIdx.x;

    const short* A; const short* B; const float* bias = nullptr;
    float* C; int N, K, lda, ldb, bm0, bn0;
    if (id < 64) {
        bm0 = (id >> 3) * 128; bn0 = (id & 7) * 128;
        A = znb; lda = 512; B = znhb; ldb = 512; C = sim; N = 1024; K = 512;
    } else if (id < 96) {
        int t = id - 64; bm0 = (t >> 2) * 128; bn0 = (t & 3) * 128;
        A = zb; lda = 512; B = w1t; ldb = 576; C = u; N = 512; K = 512; bias = b1;
    } else if (id < 128) {
        int t = id - 96; bm0 = (t >> 2) * 128; bn0 = (t & 3) * 128;
        A = znb; lda = 512; B = w2b; ldb = 512; C = v; N = 512; K = 512;
    } else {
        int t = id - 128; bm0 = (t >> 2) * 128; bn0 = (t & 3) * 128;
        A = hab; lda = 64; B = w1t + 512; ldb = 576; C = g; N = 512; K = 64;
    }

    const int lane = tid & 63, wv = tid >> 6;
    const int lm = lane & 15, lq = lane >> 4;
    const int wr = (wv >> 1) * 64, wc = (wv & 1) * 64;
    short8* A8 = (short8*)Ah; short8* B8 = (short8*)Bh;
    f32x4 acc[4][4] = {};

    for (int k0 = 0; k0 < K; k0 += 64) {
#pragma unroll
        for (int q = 0; q < 4; ++q) {
            int f = q * 256 + tid;           // 0..1023: row = f>>3, unit = f&7
            int row = f >> 3;
            int ug = (f & 7) ^ (row & 7);    // inverse swizzle on the source
            gld_lds16(&A[(bm0 + row) * lda + k0 + ug * 8],
                      &Ah[(q * 256 + wv * 64) * 8]);
            gld_lds16(&B[(bn0 + row) * ldb + k0 + ug * 8],
                      &Bh[(q * 256 + wv * 64) * 8]);
        }
        VMWAIT(0);
        raw_barrier();
#pragma unroll
        for (int kk = 0; kk < 64; kk += 32) {
            int kbi = (kk >> 3) + lq;
            short8 ah[4], bh[4];
#pragma unroll
            for (int i = 0; i < 4; ++i) ah[i] = A8[sw(wr + i * 16 + lm, kbi)];
#pragma unroll
            for (int j = 0; j < 4; ++j) bh[j] = B8[sw(wc + j * 16 + lm, kbi)];
#pragma unroll
            for (int i = 0; i < 4; ++i)
#pragma unroll
                for (int j = 0; j < 4; ++j)
                    acc[i][j] = __builtin_amdgcn_mfma_f32_16x16x32_bf16(ah[i], bh[j], acc[i][j], 0, 0, 0);
        }
        raw_barrier();
    }
#pragma unroll
    for (int i = 0; i < 4; ++i)
#pragma unroll
        for (int j = 0; j < 4; ++j) {
            int n = bn0 + wc + j * 16 + lm;
            float bb = bias ? bias[n] : 0.0f;
#pragma unroll
            for (int r = 0; r < 4; ++r) {
                int m = bm0 + wr + i * 16 + lq * 4 + r;
                C[m * N + n] = acc[i][j][r] + bb;
            }
        }
}

// ---------------------------------------------------------------------------
// neg v10 (RESTORED — the measured-best form; v11's reuse-tiling regressed
// +5us despite cutting traffic 4.4x, falsifying the traffic theory): pure
// streaming negatives, grid (1024 b, 13 s-octets) x 64 thr.  No LDS, no
// barriers; 8 independent dot chains per wave, direct L2-resident g reads.
__global__ __launch_bounds__(64, 4) void neg_kernel(
    const float* __restrict__ u, const float* __restrict__ v,
    const float* __restrict__ g, float* __restrict__ rnall)
{
    const int b = blockIdx.x, t = blockIdx.y;
    const int lane = threadIdx.x;
    const int s0 = 1 + t * 8;               // s = s0..s0+7 (valid while <= 99)

    float4 ga[8], gb[8];
#pragma unroll
    for (int c = 0; c < 8; ++c) {
        int j = (b + s0 + c) & (B_SZ - 1);  // loads always in-bounds
        ga[c] = *(const float4*)&g[j * 512 + lane * 4];
        gb[c] = *(const float4*)&g[j * 512 + 256 + lane * 4];
    }
    float4 ua = *(const float4*)&u[b * 512 + lane * 4];
    float4 ub = *(const float4*)&u[b * 512 + 256 + lane * 4];
    float4 va = *(const float4*)&v[b * 512 + lane * 4];
    float4 vb = *(const float4*)&v[b * 512 + 256 + lane * 4];

    float d[8];
#pragma unroll
    for (int c = 0; c < 8; ++c) {
        float s = 0.0f;
        s += fmaxf(ua.x + ga[c].x, 0.0f) * va.x;
        s += fmaxf(ua.y + ga[c].y, 0.0f) * va.y;
        s += fmaxf(ua.z + ga[c].z, 0.0f) * va.z;
        s += fmaxf(ua.w + ga[c].w, 0.0f) * va.w;
        s += fmaxf(ub.x + gb[c].x, 0.0f) * vb.x;
        s += fmaxf(ub.y + gb[c].y, 0.0f) * vb.y;
        s += fmaxf(ub.z + gb[c].z, 0.0f) * vb.z;
        s += fmaxf(ub.w + gb[c].w, 0.0f) * vb.w;
        d[c] = s;
    }
    for (int off = 32; off; off >>= 1) {
#pragma unroll
        for (int c = 0; c < 8; ++c) d[c] += __shfl_down(d[c], off);
    }
    if (lane == 0) {
#pragma unroll
        for (int c = 0; c < 8; ++c)
            if (s0 + c <= NNEG) rnall[b * RNP + s0 + c - 1] = d[c];
    }
}

// ---------------------------------------------------------------------------
// smax (unchanged, verified R8): 1024 blocks x 256 threads.
__global__ __launch_bounds__(256) void smax_kernel(
    const float* __restrict__ sim, const float* __restrict__ rnall,
    const float* __restrict__ z, const float* __restrict__ z_next,
    const float* __restrict__ b2, float* __restrict__ pw)
{
    const int b = blockIdx.x;
    const int tid = threadIdx.x;
    const int w = tid >> 6, lane = tid & 63;
    __shared__ float sred[12];

    float4 s4 = *(const float4*)&sim[b * 1024 + tid * 4];
    float rawn = (tid < NNEG) ? rnall[b * RNP + tid] : 0.0f;
    float diag = sim[b * 1024 + b];

    // c0: each thread covers 2 elements
    float2 z2 = *(const float2*)&z[b * 512 + tid * 2];
    float2 n2 = *(const float2*)&z_next[b * 512 + tid * 2];
    float2 c2 = *(const float2*)&b2[tid * 2];
    float p = (z2.x + c2.x) * n2.x + (z2.y + c2.y) * n2.y;
    for (int off = 32; off; off >>= 1) p += __shfl_down(p, off);
    if (lane == 0) sred[w] = p;
    __syncthreads();
    const float c0 = sred[0] + sred[1] + sred[2] + sred[3];
    __syncthreads();

    float neg = (tid < NNEG) ? (rawn + c0) : -3.4e38f;

    float m = fmaxf(fmaxf(s4.x, s4.y), fmaxf(s4.z, s4.w));
    m = fmaxf(m, neg);
    for (int off = 32; off; off >>= 1) m = fmaxf(m, __shfl_xor(m, off));
    if (lane == 0) sred[w] = m;
    __syncthreads();
    m = fmaxf(fmaxf(sred[0], sred[1]), fmaxf(sred[2], sred[3]));

    float es = 0.0f; int ck = 0;
    {
        float xs[4] = {s4.x, s4.y, s4.z, s4.w};
#pragma unroll
        for (int c = 0; c < 4; ++c) {
            int j = tid * 4 + c;
            float x = xs[c];
            es += __expf((x - m) * INV_T);
            if (x > diag) ck++;
            else if (j < b && x == diag) ck++;   // tie-break: lower index wins
        }
    }
    if (tid < NNEG) {
        es += __expf((neg - m) * INV_T);
        if (neg > diag) ck++;
    }
    float ckf = (float)ck;
    for (int off = 32; off; off >>= 1) {
        es += __shfl_down(es, off);
        ckf += __shfl_down(ckf, off);
    }
    if (lane == 0) { sred[4 + w] = es; sred[8 + w] = ckf; }
    __syncthreads();
    if (tid == 0) {
        float est = sred[4] + sred[5] + sred[6] + sred[7];
        int ckt = (int)(sred[8] + sred[9] + sred[10] + sred[11]);
        pw[b * 4 + 0] = (m - diag) * INV_T + logf(est);
        pw[b * 4 + 1] = (ckt < 1) ? 1.0f : 0.0f;
        pw[b * 4 + 2] = (ckt < 3) ? 1.0f : 0.0f;
        pw[b * 4 + 3] = (ckt < 10) ? 1.0f : 0.0f;
    }
}

// ---------------------------------------------------------------------------
// final: 1 block x 256 threads, reduce pw[1024][4] -> out[4].
__global__ __launch_bounds__(256) void final_kernel(
    const float* __restrict__ pw, float* __restrict__ out)
{
    __shared__ float red[256];
    const int tid = threadIdx.x;
    const int c = tid & 3;
    float s = 0.0f;
    for (int r = tid >> 2; r < 1024; r += 64) s += pw[r * 4 + c];
    red[tid] = s;
    __syncthreads();
    if (tid < 4) {
        float t = 0.0f;
        for (int q = 0; q < 64; ++q) t += red[tid + q * 4];
        out[tid] = t * (1.0f / (float)B_SZ);
    }
}

// ---------------------------------------------------------------------------
extern "C" void kernel_launch(void* const* d_in, const int* in_sizes, int n_in,
                              void* d_out, int out_size, void* d_ws, size_t ws_size,
                              hipStream_t stream) {
    const float* z          = (const float*)d_in[0];
    const float* z_next     = (const float*)d_in[1];
    const float* z_next_hat = (const float*)d_in[2];
    const float* actions    = (const float*)d_in[3];
    const float* Wa         = (const float*)d_in[4];
    const float* ba         = (const float*)d_in[5];
    const float* W1         = (const float*)d_in[6];
    const float* b1         = (const float*)d_in[7];
    const float* W2         = (const float*)d_in[8];
    const float* b2         = (const float*)d_in[9];
    float* out = (float*)d_out;

    float* ws    = (float*)d_ws;
    float* sim   = ws;                          // 1024*1024
    float* u     = sim + B_SZ * B_SZ;           // 1024*512
    float* v     = u + B_SZ * ZH;               // 1024*512
    float* g     = v + B_SZ * ZH;               // 1024*512
    float* pw    = g + B_SZ * ZH;               // 1024*4
    float* rnall = pw + B_SZ * 4;               // 1024*104
    short* zb    = (short*)(rnall + B_SZ * RNP);
    short* znb   = zb + B_SZ * Z_DIM;
    short* znhb  = znb + B_SZ * Z_DIM;
    short* w1t   = znhb + B_SZ * Z_DIM;         // 512*576
    short* w2b   = w1t + 512 * 576;             // 512*512
    short* hab   = w2b + 512 * 512;             // 1024*64

    cvt_kernel<<<984, 256, 0, stream>>>(z, z_next, z_next_hat, W1, W2,
                                        actions, Wa, ba,
                                        zb, znb, znhb, w1t, w2b, hab);
    mm_kernel<<<160, 256, 0, stream>>>(zb, znb, znhb, w1t, w2b, hab, b1,
                                       sim, u, v, g);
    neg_kernel<<<dim3(B_SZ, 13), 64, 0, stream>>>(u, v, g, rnall);
    smax_kernel<<<B_SZ, 256, 0, stream>>>(sim, rnall, z, z_next, b2, pw);
    final_kernel<<<1, 256, 0, stream>>>(pw, out);
}